// Round 4
// baseline (482.277 us; speedup 1.0000x reference)
//
#include <hip/hip_runtime.h>
#include <hip/hip_cooperative_groups.h>
namespace cg = cooperative_groups;

#define BB 16
#define LL 2048
#define DD 256
#define NBLK 1024
#define NTHR 256
#define PB 128           // partial-compute blocks in phase 3

typedef float vf4 __attribute__((ext_vector_type(4)));

__global__ void __launch_bounds__(NTHR, 4)
mega(const float* __restrict__ inp, const float* __restrict__ vw,
     float* __restrict__ out, float* __restrict__ ws) {
    cg::grid_group grid = cg::this_grid();
    const int blk = blockIdx.x, t = threadIdx.x;
    const int lane = t & 63, wid = t >> 6;

    float* sk      = ws;             // 32768
    float* p       = ws + 32768;     // 32768
    float* partial = ws + 65536;     // PB*DD = 32768
    float* out_vec = ws + 98304;     // 4096
    const float* wk = vw + DD;

    // ---- Phase 1: sk[row] = dot(inp[row,:], wk); 32 rows/block, 8 rows/wave
    {
        const float4 w = *reinterpret_cast<const float4*>(wk + lane * 4);
        int row0 = blk * 32 + wid * 8;
        for (int r = 0; r < 8; ++r) {
            int row = row0 + r;
            const float4 a = *reinterpret_cast<const float4*>(inp + (size_t)row * DD + lane * 4);
            float dot = a.x * w.x + a.y * w.y + a.z * w.z + a.w * w.w;
            #pragma unroll
            for (int off = 32; off >= 1; off >>= 1) dot += __shfl_down(dot, off, 64);
            if (lane == 0) sk[row] = dot;
        }
    }
    grid.sync();

    // ---- Phase 2: per-batch softmax -> p (16 blocks)
    if (blk < BB) {
        const float* skb = sk + blk * LL;
        float v[8];
        #pragma unroll
        for (int r = 0; r < 8; ++r) v[r] = skb[t + r * 256];
        float mx = v[0];
        #pragma unroll
        for (int r = 1; r < 8; ++r) mx = fmaxf(mx, v[r]);
        __shared__ float sm[4];
        __shared__ float bc;
        #pragma unroll
        for (int off = 32; off >= 1; off >>= 1) mx = fmaxf(mx, __shfl_down(mx, off, 64));
        if (lane == 0) sm[wid] = mx;
        __syncthreads();
        if (t == 0) bc = fmaxf(fmaxf(sm[0], sm[1]), fmaxf(sm[2], sm[3]));
        __syncthreads();
        float m = bc;
        float e[8], s = 0.f;
        #pragma unroll
        for (int r = 0; r < 8; ++r) { e[r] = __expf(v[r] - m); s += e[r]; }
        #pragma unroll
        for (int off = 32; off >= 1; off >>= 1) s += __shfl_down(s, off, 64);
        __syncthreads();
        if (lane == 0) sm[wid] = s;
        __syncthreads();
        if (t == 0) bc = (sm[0] + sm[1]) + (sm[2] + sm[3]);
        __syncthreads();
        float inv = 1.0f / bc;
        #pragma unroll
        for (int r = 0; r < 8; ++r) p[blk * LL + t + r * 256] = e[r] * inv;
    }
    grid.sync();

    // ---- Phase 3: split grid — partials (blk<PB) || attn broadcast write
    vf4* dst4 = (vf4*)out;
    const vf4* p4 = (const vf4*)p;
    const size_t OUT4 = (size_t)BB * LL * DD / 4;   // 2,097,152
    const size_t ATT4 = (size_t)BB * LL * LL / 4;   // 16,777,216
    if (blk < PB) {
        int b = blk >> 3, seg = blk & 7;            // 8 blocks/batch, 256 rows each
        const float* pb = p + b * LL + seg * 256;
        const float* ib = inp + ((size_t)(b * LL + seg * 256)) * DD + t;
        float acc = 0.f;
        #pragma unroll 8
        for (int j = 0; j < 256; ++j) acc += pb[j] * ib[(size_t)j * DD];
        partial[blk * DD + t] = acc;
    } else {
        const size_t stride = (size_t)(NBLK - PB) * NTHR;
        for (size_t k = (size_t)(blk - PB) * NTHR + t; k < ATT4; k += stride) {
            size_t b = k >> 20, j4 = k & 511;
            __builtin_nontemporal_store(p4[(b << 9) + j4], &dst4[OUT4 + k]);
        }
    }
    grid.sync();

    // ---- Phase 4a: reduce partials -> out_vec (16 blocks)
    if (blk < BB) {
        float acc = 0.f;
        #pragma unroll
        for (int c = 0; c < 8; ++c) acc += partial[(blk * 8 + c) * DD + t];
        out_vec[blk * DD + t] = acc;
    }
    grid.sync();

    // ---- Phase 4b: broadcast-write out region (all blocks)
    const vf4* ov4 = (const vf4*)out_vec;
    const size_t strideA = (size_t)NBLK * NTHR;
    for (size_t i = (size_t)blk * NTHR + t; i < OUT4; i += strideA) {
        size_t b = i >> 17, d4 = i & 63;
        __builtin_nontemporal_store(ov4[(b << 6) + d4], &dst4[i]);
    }
}

extern "C" void kernel_launch(void* const* d_in, const int* in_sizes, int n_in,
                              void* d_out, int out_size, void* d_ws, size_t ws_size,
                              hipStream_t stream) {
    const float* inp = (const float*)d_in[0];
    const float* vw  = (const float*)d_in[1];
    float* out = (float*)d_out;
    float* ws  = (float*)d_ws;

    void* args[] = { (void*)&inp, (void*)&vw, (void*)&out, (void*)&ws };
    hipLaunchCooperativeKernel((const void*)mega, dim3(NBLK), dim3(NTHR),
                               args, 0, stream);
}

// Round 5
// 67.204 us; speedup vs baseline: 7.1763x; 7.1763x over previous
//
#include <hip/hip_runtime.h>

#define BB 16
#define LL 2048
#define DD 256
#define PB 128                    // partial-compute blocks inside K3
#define K3BLK 2048
#define K3WR (K3BLK - PB)         // 1920 attn-writer blocks

typedef float vf4 __attribute__((ext_vector_type(4)));

// K1: sk[row] = dot(inp[row,:], wk) — one wave per row
__global__ void k1_sk(const float* __restrict__ inp, const float* __restrict__ wk,
                      float* __restrict__ sk) {
    int tid  = threadIdx.x;
    int wid  = tid >> 6, lane = tid & 63;
    int row  = blockIdx.x * 4 + wid;
    const float4 a = *reinterpret_cast<const float4*>(inp + (size_t)row * DD + lane * 4);
    const float4 w = *reinterpret_cast<const float4*>(wk + lane * 4);
    float dot = a.x * w.x + a.y * w.y + a.z * w.z + a.w * w.w;
    #pragma unroll
    for (int off = 32; off >= 1; off >>= 1) dot += __shfl_down(dot, off, 64);
    if (lane == 0) sk[row] = dot;
}

// K2: per-batch softmax over L values -> p[b,j]
__global__ void k2_softmax(const float* __restrict__ sk, float* __restrict__ p) {
    int b = blockIdx.x;
    int tid = threadIdx.x;
    int lane = tid & 63, wid = tid >> 6;
    const float* skb = sk + b * LL;
    float v[8];
    #pragma unroll
    for (int r = 0; r < 8; ++r) v[r] = skb[tid + r * 256];
    float mx = v[0];
    #pragma unroll
    for (int r = 1; r < 8; ++r) mx = fmaxf(mx, v[r]);
    __shared__ float sm[4];
    __shared__ float bc;
    #pragma unroll
    for (int off = 32; off >= 1; off >>= 1) mx = fmaxf(mx, __shfl_down(mx, off, 64));
    if (lane == 0) sm[wid] = mx;
    __syncthreads();
    if (tid == 0) bc = fmaxf(fmaxf(sm[0], sm[1]), fmaxf(sm[2], sm[3]));
    __syncthreads();
    float m = bc;
    float e[8], s = 0.f;
    #pragma unroll
    for (int r = 0; r < 8; ++r) { e[r] = __expf(v[r] - m); s += e[r]; }
    #pragma unroll
    for (int off = 32; off >= 1; off >>= 1) s += __shfl_down(s, off, 64);
    __syncthreads();
    if (lane == 0) sm[wid] = s;
    __syncthreads();
    if (tid == 0) bc = (sm[0] + sm[1]) + (sm[2] + sm[3]);
    __syncthreads();
    float inv = 1.0f / bc;
    #pragma unroll
    for (int r = 0; r < 8; ++r) p[b * LL + tid + r * 256] = e[r] * inv;
}

// K3: split grid. blk<PB: partial[b,seg,d] = sum over 256 rows of p*inp.
//     else: stream-write the 256 MiB attn region (nt stores, pure write BW).
__global__ void k3_split(const float* __restrict__ inp, const float* __restrict__ p,
                         float* __restrict__ partial, float* __restrict__ out) {
    const int blk = blockIdx.x, t = threadIdx.x;
    const size_t OUT4 = (size_t)BB * LL * DD / 4;   // 2,097,152
    const size_t ATT4 = (size_t)BB * LL * LL / 4;   // 16,777,216
    if (blk < PB) {
        int b = blk >> 3, seg = blk & 7;            // 8 segs/batch, 256 rows each
        const float* pb = p + b * LL + seg * 256;
        const float* ib = inp + ((size_t)(b * LL + seg * 256)) * DD + t;
        float acc = 0.f;
        #pragma unroll 8
        for (int j = 0; j < 256; ++j) acc += pb[j] * ib[(size_t)j * DD];
        partial[blk * DD + t] = acc;
    } else {
        vf4* dst4 = (vf4*)out + OUT4;
        const vf4* p4 = (const vf4*)p;
        const size_t stride = (size_t)K3WR * 256;
        for (size_t k = (size_t)(blk - PB) * 256 + t; k < ATT4; k += stride) {
            size_t b = k >> 20, j4 = k & 511;
            __builtin_nontemporal_store(p4[(b << 9) + j4], &dst4[k]);
        }
    }
}

// K4: out-writer. 256 blocks; each block redundantly reduces its batch's 8
//     partials into LDS (8 KB L2 read), then broadcast-writes its 128 KiB slice.
__global__ void k4_out(const float* __restrict__ partial, float* __restrict__ out) {
    const int blk = blockIdx.x, t = threadIdx.x;
    const int b = blk >> 4;                         // 16 blocks per batch
    float acc = 0.f;
    #pragma unroll
    for (int seg = 0; seg < 8; ++seg) acc += partial[(b * 8 + seg) * DD + t];
    __shared__ float ov[DD];
    ov[t] = acc;
    __syncthreads();
    const vf4* ovv = (const vf4*)ov;
    vf4* dst = (vf4*)out + (size_t)blk * 8192;      // 8192 float4 per block
    #pragma unroll 4
    for (int it = 0; it < 32; ++it) {
        int idx = it * 256 + t;
        __builtin_nontemporal_store(ovv[idx & 63], &dst[idx]);
    }
}

extern "C" void kernel_launch(void* const* d_in, const int* in_sizes, int n_in,
                              void* d_out, int out_size, void* d_ws, size_t ws_size,
                              hipStream_t stream) {
    const float* inp = (const float*)d_in[0];
    const float* vw  = (const float*)d_in[1];   // [1, 2D]: wq then wk
    float* out = (float*)d_out;
    float* ws  = (float*)d_ws;

    float* sk      = ws;             // B*L   = 32768 floats
    float* p       = ws + 32768;     // B*L   = 32768 floats
    float* partial = ws + 65536;     // PB*DD = 32768 floats

    k1_sk      <<<8192, 256, 0, stream>>>(inp, vw + DD, sk);
    k2_softmax <<<BB,   256, 0, stream>>>(sk, p);
    k3_split   <<<K3BLK,256, 0, stream>>>(inp, p, partial, out);
    k4_out     <<<256,  256, 0, stream>>>(partial, out);
}